// Round 1
// baseline (103852.661 us; speedup 1.0000x reference)
//
#include <hip/hip_runtime.h>
#include <cmath>

#define DD 1024
#define BB 64
#define TT 200
#define NWG 128

__device__ __forceinline__ float eluf(float x) { return x > 0.f ? x : expm1f(x); }

// ---------------- 1024x1024 transpose: dst[k][n] = src[n][k] ----------------
__global__ __launch_bounds__(256) void transpose_k(const float* __restrict__ src,
                                                   float* __restrict__ dst) {
  __shared__ float tile[32][33];
  const int bx = blockIdx.x << 5;   // src-row block (n)
  const int by = blockIdx.y << 5;   // src-col block (k)
  const int tx = threadIdx.x & 31;
  const int ty = threadIdx.x >> 5;  // 0..7
#pragma unroll
  for (int i = 0; i < 4; ++i) {
    int r = ty + (i << 3);
    tile[r][tx] = src[(size_t)(bx + r) * DD + by + tx];
  }
  __syncthreads();
#pragma unroll
  for (int i = 0; i < 4; ++i) {
    int r = ty + (i << 3);
    dst[(size_t)(by + r) * DD + bx + tx] = tile[tx][r];
  }
}

// ---------------- phase 0: wxT[b][n][t] = sum_k x[b][k][t]*Win[n][k] + bin[n]
// one wave per (b, t-tile(64), n-oct(8)); 32768 waves -> 8192 blocks
__global__ __launch_bounds__(256) void wx_kernel(const float* __restrict__ x,
                                                 const float* __restrict__ Win,
                                                 const float* __restrict__ bin,
                                                 float* __restrict__ wxT) {
  const int gw = (blockIdx.x << 2) | (threadIdx.x >> 6);
  const int lane = threadIdx.x & 63;
  const int noct = gw & 127;
  const int tt = (gw >> 7) & 3;
  const int b = gw >> 9;
  const int n0 = noct << 3;
  const int t = (tt << 6) + lane;
  const int tl = t < TT ? t : (TT - 1);
  const float* xp = x + (size_t)b * DD * TT + tl;
  float acc[8];
#pragma unroll
  for (int j = 0; j < 8; ++j) acc[j] = 0.f;
  for (int k = 0; k < DD; k += 4) {
    float x0 = xp[(size_t)(k + 0) * TT];
    float x1 = xp[(size_t)(k + 1) * TT];
    float x2 = xp[(size_t)(k + 2) * TT];
    float x3 = xp[(size_t)(k + 3) * TT];
#pragma unroll
    for (int j = 0; j < 8; ++j) {
      const float4 w = *(const float4*)(Win + (size_t)(n0 + j) * DD + k);
      acc[j] = fmaf(x0, w.x, fmaf(x1, w.y, fmaf(x2, w.z, fmaf(x3, w.w, acc[j]))));
    }
  }
  if (t < TT) {
#pragma unroll
    for (int j = 0; j < 8; ++j)
      wxT[((size_t)b * DD + n0 + j) * TT + t] = acc[j] + bin[n0 + j];
  }
}

// ---------------- device-wide generation barrier ----------------
__device__ __forceinline__ void grid_barrier(unsigned* cnt, unsigned* gen, unsigned g1) {
  __syncthreads();  // drains this WG's memory ops (compiler emits waitcnt before s_barrier)
  if (threadIdx.x == 0) {
    __threadfence();  // release: flush L2 so other XCDs see our stage outputs
    unsigned old = __hip_atomic_fetch_add(cnt, 1u, __ATOMIC_ACQ_REL, __HIP_MEMORY_SCOPE_AGENT);
    if (old == NWG - 1) {
      __hip_atomic_store(cnt, 0u, __ATOMIC_RELAXED, __HIP_MEMORY_SCOPE_AGENT);
      __hip_atomic_store(gen, g1, __ATOMIC_RELEASE, __HIP_MEMORY_SCOPE_AGENT);
    } else {
      while (__hip_atomic_load(gen, __ATOMIC_RELAXED, __HIP_MEMORY_SCOPE_AGENT) < g1)
        __builtin_amdgcn_s_sleep(1);
    }
    __threadfence();  // acquire: invalidate L1/L2 before reading others' outputs
  }
  __syncthreads();
}

// ---------------- one GEMM stage: out[b0+j][n] = sum_k in[b0+j][k] * Wt[k][n]
// WG tile: 8 b-rows x 64 n-cols, K split over the 4 waves, LDS reduce.
__device__ __forceinline__ void stage_gemm(const float* __restrict__ Wt,
                                           const float* __restrict__ inrows,  // inbuf + b0*DD
                                           float* __restrict__ in_s,
                                           float* __restrict__ red,
                                           int tid, int wave, int lane, int n,
                                           float& v0, float& v1) {
  {  // stage the 8 contiguous input rows (32 KB) into LDS, coalesced
    const float4* __restrict__ s4 = (const float4*)inrows;
    float4* d4 = (float4*)in_s;
#pragma unroll
    for (int i = 0; i < 8; ++i) d4[tid + (i << 8)] = s4[tid + (i << 8)];
  }
  __syncthreads();
  float acc[8];
#pragma unroll
  for (int j = 0; j < 8; ++j) acc[j] = 0.f;
  const int k0 = wave << 8;
  const float* wp = Wt + (size_t)k0 * DD + n;  // coalesced across lanes (n)
  const float* isp = in_s + k0;
  for (int kk = 0; kk < 256; kk += 4) {
    float w0 = wp[0];
    float w1 = wp[DD];
    float w2 = wp[2 * DD];
    float w3 = wp[3 * DD];
    wp += (size_t)4 * DD;
#pragma unroll
    for (int j = 0; j < 8; ++j) {
      // wave-uniform address -> LDS broadcast, conflict-free
      float4 iv = *(const float4*)(isp + j * DD + kk);
      acc[j] = fmaf(iv.x, w0, fmaf(iv.y, w1, fmaf(iv.z, w2, fmaf(iv.w, w3, acc[j]))));
    }
  }
#pragma unroll
  for (int j = 0; j < 8; ++j) red[(wave << 9) + (j << 6) + lane] = acc[j];
  __syncthreads();
  v0 = red[tid] + red[tid + 512] + red[tid + 1024] + red[tid + 1536];
  const int o2 = tid + 256;
  v1 = red[o2] + red[o2 + 512] + red[o2 + 1024] + red[o2 + 1536];
  // no trailing sync needed: next stage's in_s writes come after everyone
  // passed this function's post-kloop __syncthreads (program order).
}

// ---------------- phase 1: the whole sequential scan, one cooperative kernel
__global__ void __launch_bounds__(256, 1) rnn_kernel(
    const float* __restrict__ WtH, const float* __restrict__ Wt2,
    const float* __restrict__ Wt3, const float* __restrict__ WtO,
    const float* __restrict__ bh_, const float* __restrict__ b2_,
    const float* __restrict__ b3_, const float* __restrict__ bo_,
    const float* __restrict__ etas_, const float* __restrict__ wxT,
    float* __restrict__ sbuf, float* __restrict__ F1b, float* __restrict__ Gb,
    float* __restrict__ hb, float* __restrict__ h0b, float* __restrict__ outp,
    unsigned* __restrict__ bar) {
  __shared__ float in_s[8192];  // 32 KB: 8 rows x 1024
  __shared__ float red[2048];   // 8 KB: 4 waves x 512 outputs
  const int tid = threadIdx.x;
  const int wave = tid >> 6, lane = tid & 63;
  const int ntile = blockIdx.x & 15, btile = blockIdx.x >> 4;  // blk%8 = ntile%8 -> XCD-local W slice
  const int n = (ntile << 6) | lane;
  const int b0 = btile << 3;

  const float bh = bh_[n], bb2 = b2_[n], bb3 = b3_[n], bo = bo_[n];
  float eta[5];
#pragma unroll
  for (int i = 0; i < 5; ++i) eta[i] = etas_[i];

  const int rb0 = b0 + wave;      // b-row of this thread's v0 output
  const int rb1 = b0 + wave + 4;  // b-row of v1
  const size_t o0 = (size_t)rb0 * DD + n;
  const size_t o1 = (size_t)rb1 * DD + n;

  const float* inoff_s = sbuf + (size_t)b0 * DD;
  const float* inoff_F = F1b + (size_t)b0 * DD;
  const float* inoff_G = Gb + (size_t)b0 * DD;
  const float* inoff_h = hb + (size_t)b0 * DD;

  unsigned g = 0;
  float v0, v1;
  for (int t = 0; t < TT; ++t) {
    for (int it = 0; it < 5; ++it) {
      if (it == 0 && t > 0) {
        // output GEMM for previous step; shares this barrier window with stage A
        stage_gemm(WtO, inoff_h, in_s, red, tid, wave, lane, n, v0, v1);
        outp[o0 * TT + (t - 1)] = v0 + bo;
        outp[o1 * TT + (t - 1)] = v1 + bo;
      }
      // ---- stage A: F1 = elu((h+h0)@Whid^T + bh + wx)
      stage_gemm(WtH, inoff_s, in_s, red, tid, wave, lane, n, v0, v1);
      {
        float u0 = v0 + bh + wxT[o0 * TT + t];
        float u1 = v1 + bh + wxT[o1 * TT + t];
        F1b[o0] = eluf(u0);
        F1b[o1] = eluf(u1);
      }
      grid_barrier(bar, bar + 32, ++g);
      // ---- stage B: G = elu(F1@W2^T + b2)
      stage_gemm(Wt2, inoff_F, in_s, red, tid, wave, lane, n, v0, v1);
      Gb[o0] = eluf(v0 + bb2);
      Gb[o1] = eluf(v1 + bb2);
      grid_barrier(bar, bar + 32, ++g);
      // ---- stage C: Fn = elu(G@W3^T + b3); h += eta*(Fn - h - h0)
      stage_gemm(Wt3, inoff_G, in_s, red, tid, wave, lane, n, v0, v1);
      {
        float fn0 = eluf(v0 + bb3), fn1 = eluf(v1 + bb3);
        float h_0 = hb[o0], h_1 = hb[o1];
        float q0 = h0b[o0], q1 = h0b[o1];
        float e = eta[it];
        float hn0 = h_0 + e * (fn0 - h_0 - q0);
        float hn1 = h_1 + e * (fn1 - h_1 - q1);
        hb[o0] = hn0;
        hb[o1] = hn1;
        if (it == 4) {  // step transition: h0 <- h_t, s <- h_t + h_t
          h0b[o0] = hn0;
          h0b[o1] = hn1;
          sbuf[o0] = 2.f * hn0;
          sbuf[o1] = 2.f * hn1;
        } else {  // s <- h_new + h0 for next stage A
          sbuf[o0] = hn0 + q0;
          sbuf[o1] = hn1 + q1;
        }
      }
      grid_barrier(bar, bar + 32, ++g);
    }
  }
  // final output GEMM for t = TT-1
  stage_gemm(WtO, inoff_h, in_s, red, tid, wave, lane, n, v0, v1);
  outp[o0 * TT + (TT - 1)] = v0 + bo;
  outp[o1 * TT + (TT - 1)] = v1 + bo;
}

extern "C" void kernel_launch(void* const* d_in, const int* in_sizes, int n_in,
                              void* d_out, int out_size, void* d_ws, size_t ws_size,
                              hipStream_t stream) {
  const float* x = (const float*)d_in[0];
  const float* Win = (const float*)d_in[1];
  const float* bin = (const float*)d_in[2];
  const float* Whid = (const float*)d_in[3];
  const float* bhid = (const float*)d_in[4];
  const float* W2 = (const float*)d_in[5];
  const float* b2 = (const float*)d_in[6];
  const float* W3 = (const float*)d_in[7];
  const float* b3 = (const float*)d_in[8];
  const float* Wout = (const float*)d_in[9];
  const float* bout = (const float*)d_in[10];
  const float* etas = (const float*)d_in[11];
  float* out = (float*)d_out;

  char* ws = (char*)d_ws;
  float* wxT = (float*)(ws);                  // 52,428,800 B  [B][D][T]
  float* WtH = (float*)(ws + 52428800);       // 4 MB each, k-major weights
  float* Wt2 = (float*)(ws + 56623104);
  float* Wt3 = (float*)(ws + 60817408);
  float* WtO = (float*)(ws + 65011712);
  float* sbuf = (float*)(ws + 69206016);      // 256 KB each
  float* F1b = (float*)(ws + 69468160);
  float* Gb = (float*)(ws + 69730304);
  float* hb = (float*)(ws + 69992448);
  float* h0b = (float*)(ws + 70254592);
  unsigned* bar = (unsigned*)(ws + 70516736); // barrier cnt/gen
  // total ws use: ~70.6 MB

  hipMemsetAsync(sbuf, 0, 262144, stream);
  hipMemsetAsync(hb, 0, 262144, stream);
  hipMemsetAsync(h0b, 0, 262144, stream);
  hipMemsetAsync(bar, 0, 256, stream);

  dim3 tb(256);
  dim3 tg(32, 32);
  hipLaunchKernelGGL(transpose_k, tg, tb, 0, stream, Whid, WtH);
  hipLaunchKernelGGL(transpose_k, tg, tb, 0, stream, W2, Wt2);
  hipLaunchKernelGGL(transpose_k, tg, tb, 0, stream, W3, Wt3);
  hipLaunchKernelGGL(transpose_k, tg, tb, 0, stream, Wout, WtO);
  hipLaunchKernelGGL(wx_kernel, dim3(8192), tb, 0, stream, x, Win, bin, wxT);

  void* args[] = {&WtH, &Wt2, &Wt3, &WtO, &bhid, &b2, &b3, &bout, &etas,
                  &wxT, &sbuf, &F1b, &Gb, &hb, &h0b, &out, &bar};
  hipLaunchCooperativeKernel((void*)rnn_kernel, dim3(NWG), tb, args, 0, stream);
}

// Round 3
// 88843.573 us; speedup vs baseline: 1.1689x; 1.1689x over previous
//
#include <hip/hip_runtime.h>
#include <cmath>

#define DD 1024
#define TT 200
#define NWG 256
#define THR 512

__device__ __forceinline__ float eluf(float x) { return x > 0.f ? x : expm1f(x); }

// ---------------- 1024x1024 transpose: dst[k][n] = src[n][k] ----------------
__global__ __launch_bounds__(256) void transpose_k(const float* __restrict__ src,
                                                   float* __restrict__ dst) {
  __shared__ float tile[32][33];
  const int bx = blockIdx.x << 5;
  const int by = blockIdx.y << 5;
  const int tx = threadIdx.x & 31;
  const int ty = threadIdx.x >> 5;
#pragma unroll
  for (int i = 0; i < 4; ++i) {
    int r = ty + (i << 3);
    tile[r][tx] = src[(size_t)(bx + r) * DD + by + tx];
  }
  __syncthreads();
#pragma unroll
  for (int i = 0; i < 4; ++i) {
    int r = ty + (i << 3);
    dst[(size_t)(by + r) * DD + bx + tx] = tile[tx][r];
  }
}

// ---------------- phase 0: wxT[b][n][t] = sum_k x[b][k][t]*Win[n][k] + bin[n]
__global__ __launch_bounds__(256) void wx_kernel(const float* __restrict__ x,
                                                 const float* __restrict__ Win,
                                                 const float* __restrict__ bin,
                                                 float* __restrict__ wxT) {
  const int gw = (blockIdx.x << 2) | (threadIdx.x >> 6);
  const int lane = threadIdx.x & 63;
  const int noct = gw & 127;
  const int tt = (gw >> 7) & 3;
  const int b = gw >> 9;
  const int n0 = noct << 3;
  const int t = (tt << 6) + lane;
  const int tl = t < TT ? t : (TT - 1);
  const float* xp = x + (size_t)b * DD * TT + tl;
  float acc[8];
#pragma unroll
  for (int j = 0; j < 8; ++j) acc[j] = 0.f;
  for (int k = 0; k < DD; k += 4) {
    float x0 = xp[(size_t)(k + 0) * TT];
    float x1 = xp[(size_t)(k + 1) * TT];
    float x2 = xp[(size_t)(k + 2) * TT];
    float x3 = xp[(size_t)(k + 3) * TT];
#pragma unroll
    for (int j = 0; j < 8; ++j) {
      const float4 w = *(const float4*)(Win + (size_t)(n0 + j) * DD + k);
      acc[j] = fmaf(x0, w.x, fmaf(x1, w.y, fmaf(x2, w.z, fmaf(x3, w.w, acc[j]))));
    }
  }
  if (t < TT) {
#pragma unroll
    for (int j = 0; j < 8; ++j)
      wxT[((size_t)b * DD + n0 + j) * TT + t] = acc[j] + bin[n0 + j];
  }
}

// ---------------- device-wide generation barrier (round-1 proven protocol) --
__device__ __forceinline__ void grid_barrier(unsigned* cnt, unsigned* gen, unsigned g1) {
  __syncthreads();
  if (threadIdx.x == 0) {
    __threadfence();  // release: write back dirty L2 (activations) to MALL
    unsigned old = __hip_atomic_fetch_add(cnt, 1u, __ATOMIC_ACQ_REL, __HIP_MEMORY_SCOPE_AGENT);
    if (old == NWG - 1) {
      __hip_atomic_store(cnt, 0u, __ATOMIC_RELAXED, __HIP_MEMORY_SCOPE_AGENT);
      __hip_atomic_store(gen, g1, __ATOMIC_RELEASE, __HIP_MEMORY_SCOPE_AGENT);
    } else {
      while (__hip_atomic_load(gen, __ATOMIC_RELAXED, __HIP_MEMORY_SCOPE_AGENT) < g1)
        __builtin_amdgcn_s_sleep(1);
    }
    __threadfence();  // acquire: invalidate CU L0 + XCD L2 before reading peers' data
  }
  __syncthreads();
}

// ---------------- one GEMM stage: out[b0+r][n] = sum_k in[b0+r][k]*Wt[k][n]
// WG: 512 thr = 8 waves. Tile 8 b-rows x 32 n-cols. Wave = k-eighth (128).
// Thread: 1 n-col (nl), 4 b-rows (half-wave bg). Weights 8-deep double-buffered.
__device__ __forceinline__ float stage_gemm(const float* __restrict__ Wt,
                                            const float* __restrict__ inrows,
                                            float* __restrict__ in_s,
                                            float* __restrict__ red,
                                            int tid, int k0, int nn, int bg) {
  {  // stage 8 rows (32 KB) into LDS: 4 float4 per thread, coalesced
    const float4* __restrict__ s4 = (const float4*)inrows;
    float4* d4 = (float4*)in_s;
    float4 t0 = s4[tid], t1 = s4[tid + 512], t2 = s4[tid + 1024], t3 = s4[tid + 1536];
    d4[tid] = t0;
    d4[tid + 512] = t1;
    d4[tid + 1024] = t2;
    d4[tid + 1536] = t3;
  }
  __syncthreads();

  const float* wp = Wt + (size_t)k0 * DD + nn;  // lane-coalesced over n
  const float* isp = in_s + ((bg << 2) << 10) + k0;
  float acc[4];
#pragma unroll
  for (int j = 0; j < 4; ++j) acc[j] = 0.f;
  float wa[8], wb[8];
#pragma unroll
  for (int j = 0; j < 8; ++j) wa[j] = wp[j * DD];

#pragma unroll
  for (int kk = 0; kk < 128; kk += 16) {
#pragma unroll
    for (int j = 0; j < 8; ++j) wb[j] = wp[(kk + 8 + j) * DD];
#pragma unroll
    for (int rr = 0; rr < 4; ++rr) {
      const float4 a = *(const float4*)(isp + (rr << 10) + kk);  // LDS bcast/half-wave
      const float4 b = *(const float4*)(isp + (rr << 10) + kk + 4);
      acc[rr] = fmaf(a.x, wa[0], fmaf(a.y, wa[1], fmaf(a.z, wa[2], fmaf(a.w, wa[3], acc[rr]))));
      acc[rr] = fmaf(b.x, wa[4], fmaf(b.y, wa[5], fmaf(b.z, wa[6], fmaf(b.w, wa[7], acc[rr]))));
    }
#pragma unroll
    for (int j = 0; j < 8; ++j) wa[j] = wp[((kk + 16 + j) & 127) * DD];  // wrap: in-bounds
#pragma unroll
    for (int rr = 0; rr < 4; ++rr) {
      const float4 a = *(const float4*)(isp + (rr << 10) + kk + 8);
      const float4 b = *(const float4*)(isp + (rr << 10) + kk + 12);
      acc[rr] = fmaf(a.x, wb[0], fmaf(a.y, wb[1], fmaf(a.z, wb[2], fmaf(a.w, wb[3], acc[rr]))));
      acc[rr] = fmaf(b.x, wb[4], fmaf(b.y, wb[5], fmaf(b.z, wb[6], fmaf(b.w, wb[7], acc[rr]))));
    }
  }

  // cross-wave K reduction through LDS
  const int ob = ((tid >> 6) << 8) + (bg << 7) + (nn & 31);
  red[ob] = acc[0];
  red[ob + 32] = acc[1];
  red[ob + 64] = acc[2];
  red[ob + 96] = acc[3];
  __syncthreads();
  float v = 0.f;
  if (tid < 256) {
#pragma unroll
    for (int w = 0; w < 8; ++w) v += red[(w << 8) + tid];
  }
  return v;
}

// ---------------- the whole sequential scan, one cooperative kernel --------
__global__ void __launch_bounds__(THR, 1) rnn_kernel(
    const float* __restrict__ WtH, const float* __restrict__ Wt2,
    const float* __restrict__ Wt3, const float* __restrict__ WtO,
    const float* __restrict__ bh_, const float* __restrict__ b2_,
    const float* __restrict__ b3_, const float* __restrict__ bo_,
    const float* __restrict__ etas_, const float* __restrict__ wxT,
    float* __restrict__ sbuf, float* __restrict__ F1b, float* __restrict__ Gb,
    float* __restrict__ hb, float* __restrict__ outp,
    unsigned* __restrict__ bar) {
  __shared__ float in_s[8192];  // 32 KB
  __shared__ float red[2048];   // 8 KB
  const int tid = threadIdx.x;
  const int lane = tid & 63;
  const int ntile = blockIdx.x & 31;  // blk%8 -> XCD: weight slices L2/IF$-local
  const int btile = blockIdx.x >> 5;
  const int n0 = ntile << 5;
  const int b0 = btile << 3;
  const int nl = lane & 31;
  const int bg = lane >> 5;
  const int nn = n0 + nl;
  const int k0 = (tid >> 6) << 7;  // wave's 128-k slice

  const bool owner = tid < 256;  // threads that own one output element
  const int orow = (tid & 255) >> 5;
  const int ocol = tid & 31;
  const size_t o = (size_t)(b0 + orow) * DD + (n0 + ocol);

  const float bh = bh_[n0 + ocol], bb2 = b2_[n0 + ocol];
  const float bb3 = b3_[n0 + ocol], bo = bo_[n0 + ocol];
  float eta[5];
#pragma unroll
  for (int i = 0; i < 5; ++i) eta[i] = etas_[i];

  const float* in_sb = sbuf + (size_t)b0 * DD;
  const float* in_F = F1b + (size_t)b0 * DD;
  const float* in_G = Gb + (size_t)b0 * DD;
  const float* in_h = hb + (size_t)b0 * DD;
  const float* wxp = wxT + o * TT;

  float h = 0.f, h0 = 0.f;  // private h-element (owner threads only)
  unsigned g = 0;
  for (int t = 0; t < TT; ++t) {
    for (int it = 0; it < 5; ++it) {
      if (it == 0 && t > 0) {
        // output GEMM for previous step shares this barrier window with stage A
        float v = stage_gemm(WtO, in_h, in_s, red, tid, k0, nn, bg);
        if (owner) outp[o * TT + (t - 1)] = v + bo;
      }
      // stage A: F1 = elu((h+h0)@Whid^T + bh + wx)
      float v = stage_gemm(WtH, in_sb, in_s, red, tid, k0, nn, bg);
      if (owner) F1b[o] = eluf(v + bh + wxp[t]);
      grid_barrier(bar, bar + 32, ++g);
      // stage B: G = elu(F1@W2^T + b2)
      v = stage_gemm(Wt2, in_F, in_s, red, tid, k0, nn, bg);
      if (owner) Gb[o] = eluf(v + bb2);
      grid_barrier(bar, bar + 32, ++g);
      // stage C: Fn = elu(G@W3^T + b3); h += eta*(Fn - h - h0)
      v = stage_gemm(Wt3, in_G, in_s, red, tid, k0, nn, bg);
      if (owner) {
        float fn = eluf(v + bb3);
        float e = eta[it];
        h += e * (fn - h - h0);
        if (it == 4) {  // step transition: h0 <- h_t, s <- 2*h_t
          h0 = h;
          sbuf[o] = 2.f * h;
          hb[o] = h;  // consumed by next window's output GEMM
        } else {
          sbuf[o] = h + h0;
        }
      }
      grid_barrier(bar, bar + 32, ++g);
    }
  }
  float v = stage_gemm(WtO, in_h, in_s, red, tid, k0, nn, bg);
  if (owner) outp[o * TT + (TT - 1)] = v + bo;
}

extern "C" void kernel_launch(void* const* d_in, const int* in_sizes, int n_in,
                              void* d_out, int out_size, void* d_ws, size_t ws_size,
                              hipStream_t stream) {
  const float* x = (const float*)d_in[0];
  const float* Win = (const float*)d_in[1];
  const float* bin = (const float*)d_in[2];
  const float* Whid = (const float*)d_in[3];
  const float* bhid = (const float*)d_in[4];
  const float* W2 = (const float*)d_in[5];
  const float* b2 = (const float*)d_in[6];
  const float* W3 = (const float*)d_in[7];
  const float* b3 = (const float*)d_in[8];
  const float* Wout = (const float*)d_in[9];
  const float* bout = (const float*)d_in[10];
  const float* etas = (const float*)d_in[11];
  float* out = (float*)d_out;

  char* ws = (char*)d_ws;
  float* wxT = (float*)(ws);                   // 52.4 MB  [B][D][T]
  float* WtH = (float*)(ws + 52428800);        // 4 MB each, k-major
  float* Wt2 = (float*)(ws + 56623104);
  float* Wt3 = (float*)(ws + 60817408);
  float* WtO = (float*)(ws + 65011712);
  float* sbuf = (float*)(ws + 69206016);       // 256 KB each
  float* F1b = (float*)(ws + 69468160);
  float* Gb = (float*)(ws + 69730304);
  float* hb = (float*)(ws + 69992448);
  unsigned* bar = (unsigned*)(ws + 70516736);  // cnt @+0, gen @+128B

  hipMemsetAsync(sbuf, 0, 262144, stream);
  hipMemsetAsync(bar, 0, 256, stream);

  dim3 tb(256);
  dim3 tg(32, 32);
  hipLaunchKernelGGL(transpose_k, tg, tb, 0, stream, Whid, WtH);
  hipLaunchKernelGGL(transpose_k, tg, tb, 0, stream, W2, Wt2);
  hipLaunchKernelGGL(transpose_k, tg, tb, 0, stream, W3, Wt3);
  hipLaunchKernelGGL(transpose_k, tg, tb, 0, stream, Wout, WtO);
  hipLaunchKernelGGL(wx_kernel, dim3(8192), tb, 0, stream, x, Win, bin, wxT);

  void* args[] = {&WtH, &Wt2, &Wt3, &WtO, &bhid, &b2, &b3, &bout, &etas,
                  &wxT, &sbuf, &F1b, &Gb, &hb, &out, &bar};
  hipLaunchCooperativeKernel((void*)rnn_kernel, dim3(NWG), dim3(THR), args, 0, stream);
}